// Round 1
// baseline (110.215 us; speedup 1.0000x reference)
//
#include <hip/hip_runtime.h>
#include <hip/hip_bf16.h>

typedef unsigned int u32;
typedef unsigned long long u64;
typedef __attribute__((ext_vector_type(8))) short bf16x8;
typedef __attribute__((ext_vector_type(4))) float f32x4;
typedef __attribute__((ext_vector_type(4))) u32 u32x4;

#define NB 128
#define PP 200
#define KK 60
#define NN (NB*PP)      // 25600
#define HH 64

// d_out is FLOAT32. Offsets in f32 elements: out, pos, batch, edge(src,dst)
#define OUT_OFF   0
#define POS_OFF   (NN*HH)             // 1638400
#define BATCH_OFF (POS_OFF + NN*3)    // 1715200
#define ESRC_OFF  (BATCH_OFF + NN)    // 1740800
#define EDST_OFF  (ESRC_OFF + NN*KK)  // 3276800

// truncating bf16x2 pack in ONE v_perm_b32: D = (hi16 of b)<<16 | (hi16 of a)
static __device__ __forceinline__ u32 packtr(float a, float b) {
    return __builtin_amdgcn_perm(__float_as_uint(b), __float_as_uint(a), 0x07060302u);
}
static __device__ __forceinline__ u32 prefix_lt(u64 b) {   // #set bits below lane
    return __builtin_amdgcn_mbcnt_hi((u32)(b >> 32),
                                     __builtin_amdgcn_mbcnt_lo((u32)b, 0));
}

// ---------------------------------------------------------------------------
// FUSED kernel: block = 8 consecutive targets of one event; wave = 2 targets.
// Phase A: stage event x/pos AND block-level PACKED weights to LDS.
// Phase B: per-wave keys, skip-done interleaved ballot binary searches,
//   ballot+mbcnt compaction -> jslot LDS only; coalesced ESRC/EDST stores.
// Phase C: msg build, layer-1 MFMA, REGISTER repack via
//   permlane32_swap+permlane16_swap (no LDS round trip), layer-2 MFMA,
//   raw-acc max, full-wave coalesced output store.
// ---------------------------------------------------------------------------
__global__ __launch_bounds__(256) void fused_kernel(const float* __restrict__ x,
                                                    const float* __restrict__ pos,
                                                    const float* __restrict__ W1,
                                                    const float* __restrict__ b1p,
                                                    const float* __restrict__ W2,
                                                    const float* __restrict__ b2p,
                                                    float* __restrict__ out) {
    __shared__ alignas(16) float xs[PP * 4];       // 3200 B
    __shared__ alignas(16) float psl[PP * 3];      // 2400 B
    __shared__ alignas(16) u32 jslot[4 * 128];     // 2048 B
    __shared__ alignas(16) u32 msg[4 * 256];       // 4096 B
    __shared__ alignas(16) u32 pkW1[64 * 4];       // 1024 B  [m][d] pk(W1 rows 2d,2d+1 / b1)
    __shared__ alignas(16) u32 pkW2T[64 * 33];     // 8448 B  [col][kp] pk(W2 rows 2kp,2kp+1), stride 33
    __shared__ alignas(16) float b2s[64];          // 256 B
    __shared__ alignas(16) u32 zrow[4];            // 16 B zero B-frag row

    int tid = threadIdx.x, blk = blockIdx.x;
    int e = blk / 25;
    int pl0b = (blk % 25) * 8;
    int i0b  = e * PP + pl0b;

    if (tid < 200) ((f32x4*)xs)[tid]  = ((const f32x4*)x)[e * PP + tid];
    if (tid < 150) ((f32x4*)psl)[tid] = ((const f32x4*)pos)[e * 150 + tid];
    if (tid < 4)   zrow[tid] = 0u;

    // ---- block-level packed-weight staging (amortizes per-wave packing) ----
    {   // pkW1: 256 entries, one per thread: m = tid&63, d = tid>>6
        int m = tid & 63, d = tid >> 6;
        float hiv = (d < 3) ? W1[(2*d + 1)*64 + m] : b1p[m];   // bias in slot 7
        pkW1[m*4 + d] = packtr(W1[(2*d)*64 + m], hiv);
    }
    #pragma unroll
    for (int r = 0; r < 8; ++r) {                 // pkW2T: 2048 entries
        int idx = r * 256 + tid;
        int kp = idx >> 6, col = idx & 63;
        pkW2T[col*33 + kp] = packtr(W2[(2*kp)*64 + col], W2[(2*kp + 1)*64 + col]);
    }
    if (tid < 64) b2s[tid] = b2p[tid];
    __syncthreads();

    if (tid < 24) out[POS_OFF + i0b * 3 + tid] = psl[pl0b * 3 + tid];
    if (tid < 8)  out[BATCH_OFF + i0b + tid] = (float)e;

    int lane = tid & 63, wv = tid >> 6;
    int lo16 = lane & 15, hi16 = lane >> 4;
    int plA = pl0b + wv * 2, plB = plA + 1;
    int iA = e * PP + plA,   iB = iA + 1;

    // ---------------- Phase B: KNN for two targets ----------------
    float axA = psl[plA*3], ayA = psl[plA*3+1], azA = psl[plA*3+2];
    float axB = psl[plB*3], ayB = psl[plB*3+1], azB = psl[plB*3+2];

    u32 keyA[4], keyB[4];
    #pragma unroll
    for (int q = 0; q < 4; ++q) {
        int j = lane + q * 64;
        int jc = (j < PP) ? j : 0;
        float px = psl[jc*3], py = psl[jc*3+1], pz = psl[jc*3+2];
        float dxA = px-axA, dyA = py-ayA, dzA = pz-azA;
        float dxB = px-axB, dyB = py-ayB, dzB = pz-azB;
        float d2A = dxA*dxA + dyA*dyA + dzA*dzA;
        float d2B = dxB*dxB + dyB*dyB + dzB*dzB;
        keyA[q] = (j < PP && j != plA)
                ? ((__float_as_uint(d2A) & 0xFFFFFF00u) | (u32)j) : 0xFFFFFFFFu;
        keyB[q] = (j < PP && j != plB)
                ? ((__float_as_uint(d2B) & 0xFFFFFF00u) | (u32)j) : 0xFFFFFFFFu;
    }

    // skip-done interleaved searches: once a target is done its 4 ballots
    // are skipped (wave-uniform branch). Exit on cnt==60 or width<=1
    // (keys unique => cnt(hi)==60 at width 1).
    u32 loA = 0u, hiA = 0x7F800000u, loB = 0u, hiB = 0x7F800000u;
    int doneA = 0, doneB = 0;
    #pragma unroll 1
    for (int it = 0; it < 40; ++it) {
        if (!doneA) {
            u32 mA = loA + ((hiA - loA) >> 1);
            int cA = __builtin_popcountll(__ballot(keyA[0] < mA))
                   + __builtin_popcountll(__ballot(keyA[1] < mA))
                   + __builtin_popcountll(__ballot(keyA[2] < mA))
                   + __builtin_popcountll(__ballot(keyA[3] < mA));
            if (cA >= KK) hiA = mA; else loA = mA;
            doneA = (cA == KK) | (hiA - loA <= 1u);
        }
        if (!doneB) {
            u32 mB = loB + ((hiB - loB) >> 1);
            int cB = __builtin_popcountll(__ballot(keyB[0] < mB))
                   + __builtin_popcountll(__ballot(keyB[1] < mB))
                   + __builtin_popcountll(__ballot(keyB[2] < mB))
                   + __builtin_popcountll(__ballot(keyB[3] < mB));
            if (cB >= KK) hiB = mB; else loB = mB;
            doneB = (cB == KK) | (hiB - loB <= 1u);
        }
        if (doneA & doneB) break;
    }

    const int jsb = wv * 128;
    if (lane >= KK) {                            // slots 60..63 = self id
        jslot[jsb + lane]      = (u32)plA;
        jslot[jsb + 64 + lane] = (u32)plB;
    }
    #pragma unroll
    for (int t = 0; t < 2; ++t) {
        const u32* key = t ? keyB : keyA;
        u32 hh = t ? hiB : hiA;
        u64 m0 = __ballot(key[0] < hh);
        u64 m1 = __ballot(key[1] < hh);
        u64 m2 = __ballot(key[2] < hh);
        u64 m3 = __ballot(key[3] < hh);
        u32 s1 = (u32)__builtin_popcountll(m0);
        u32 s2 = s1 + (u32)__builtin_popcountll(m1);
        u32 s3 = s2 + (u32)__builtin_popcountll(m2);
        u32 sl[4] = { prefix_lt(m0), s1 + prefix_lt(m1),
                      s2 + prefix_lt(m2), s3 + prefix_lt(m3) };
        #pragma unroll
        for (int q = 0; q < 4; ++q)
            if (key[q] < hh) jslot[jsb + t * 64 + (int)sl[q]] = key[q] & 0xFFu;
    }
    // coalesced edge outputs from jslot (replaces scattered global stores)
    if (lane < KK) {
        out[ESRC_OFF + iA * KK + lane] = (float)(e * PP + (int)jslot[jsb + lane]);
        out[ESRC_OFF + iB * KK + lane] = (float)(e * PP + (int)jslot[jsb + 64 + lane]);
        out[EDST_OFF + iA * KK + lane] = (float)iA;
        out[EDST_OFF + iB * KK + lane] = (float)iB;
    }

    // ---------------- weights: per-wave fragment loads from LDS ----------------
    bf16x8 w1f[4];
    #pragma unroll
    for (int th = 0; th < 4; ++th) {
        union { u32 w[4]; bf16x8 v; } u;
        if (hi16 == 0) *(u32x4*)u.w = *(const u32x4*)&pkW1[(th * 16 + lo16) * 4];
        else { u.w[0] = u.w[1] = u.w[2] = u.w[3] = 0u; }
        w1f[th] = u.v;
    }
    bf16x8 bfr[4][2];
    #pragma unroll
    for (int t = 0; t < 4; ++t)
        #pragma unroll
        for (int s = 0; s < 2; ++s) {
            union { u32 w[4]; bf16x8 v; } u;
            int base = (t * 16 + lo16) * 33 + s * 16 + hi16 * 4;
            #pragma unroll
            for (int d = 0; d < 4; ++d) u.w[d] = pkW2T[base + d];
            bfr[t][s] = u.v;
        }
    float b2me = b2s[lane];                       // this lane's output column bias

    // ---------------- Phase C: MLP + max-aggregate ----------------
    const int msb = wv * 256;
    const u32* mbase = (hi16 == 0) ? &msg[msb + lo16 * 4] : zrow;
    const int mstep  = (hi16 == 0) ? 64 : 0;

    for (int tl = 0; tl < 2; ++tl) {
        int i = iA + tl, pl = plA + tl;
        int jloc = (int)jslot[jsb + tl * 64 + lane];
        f32x4 xv = ((const f32x4*)xs)[jloc];
        float rx = psl[jloc*3]   - psl[pl*3];
        float ry = psl[jloc*3+1] - psl[pl*3+1];
        float rz = psl[jloc*3+2] - psl[pl*3+2];
        u32x4 mrow;
        mrow[0] = packtr(xv[0], xv[1]);
        mrow[1] = packtr(xv[2], xv[3]);
        mrow[2] = packtr(rx, ry);
        mrow[3] = packtr(rz, 1.0f);
        *(u32x4*)&msg[msb + lane * 4] = mrow;

        float rmax[4] = {-3.0e38f, -3.0e38f, -3.0e38f, -3.0e38f};
        #pragma unroll
        for (int rt = 0; rt < 4; ++rt) {
            union { u32 w[4]; bf16x8 v; } mu;
            *(u32x4*)mu.w = *(const u32x4*)(mbase + rt * mstep);

            f32x4 c1[4];
            #pragma unroll
            for (int th = 0; th < 4; ++th)
                c1[th] = __builtin_amdgcn_mfma_f32_16x16x32_bf16(w1f[th], mu.v,
                                                                 (f32x4)0.f, 0, 0, 0);
            f32x4 acc[4];
            #pragma unroll
            for (int t = 0; t < 4; ++t) acc[t] = (f32x4)0.f;

            #pragma unroll
            for (int s = 0; s < 2; ++s) {
                // Pe = pk(c1[2s]), Po = pk(c1[2s+1]) after ReLU
                u32 pe0 = packtr(fmaxf(c1[2*s][0], 0.f), fmaxf(c1[2*s][1], 0.f));
                u32 pe1 = packtr(fmaxf(c1[2*s][2], 0.f), fmaxf(c1[2*s][3], 0.f));
                u32 po0 = packtr(fmaxf(c1[2*s+1][0], 0.f), fmaxf(c1[2*s+1][1], 0.f));
                u32 po1 = packtr(fmaxf(c1[2*s+1][2], 0.f), fmaxf(c1[2*s+1][3], 0.f));
                // register repack replacing the af LDS round trip:
                // permlane32_swap: (a,b) -> ([a0,a1,b0,b1],[a2,a3,b2,b3])
                // permlane16_swap: (x,y) -> ([x0,y0,x2,y2],[x1,y1,x3,y3])
                // net: u[pq]=[a0,a2,b0,b2], u[2+pq]=[a1,a3,b1,b3]
                union { u32 w[4]; bf16x8 v; } u;
                {
                    auto t0 = __builtin_amdgcn_permlane32_swap(pe0, po0, false, false);
                    auto w0 = __builtin_amdgcn_permlane16_swap(t0[0], t0[1], false, false);
                    u.w[0] = w0[0]; u.w[2] = w0[1];
                }
                {
                    auto t1 = __builtin_amdgcn_permlane32_swap(pe1, po1, false, false);
                    auto w1 = __builtin_amdgcn_permlane16_swap(t1[0], t1[1], false, false);
                    u.w[1] = w1[0]; u.w[3] = w1[1];
                }
                #pragma unroll
                for (int t = 0; t < 4; ++t)
                    acc[t] = __builtin_amdgcn_mfma_f32_16x16x32_bf16(u.v, bfr[t][s],
                                                                     acc[t], 0, 0, 0);
            }
            // raw-acc max; +b2 and relu commute past the row-max
            #pragma unroll
            for (int t = 0; t < 4; ++t) {
                rmax[t] = fmaxf(fmaxf(acc[t][0], acc[t][1]), rmax[t]);
                rmax[t] = fmaxf(fmaxf(acc[t][2], acc[t][3]), rmax[t]);
            }
        }
        #pragma unroll
        for (int t = 0; t < 4; ++t) {
            rmax[t] = fmaxf(rmax[t], __shfl_xor(rmax[t], 16, 64));
            rmax[t] = fmaxf(rmax[t], __shfl_xor(rmax[t], 32, 64));
        }
        // full-wave coalesced output row: lane stores col=lane -> needs rmax[lane>>4]
        float sel = rmax[0];
        sel = (hi16 == 1) ? rmax[1] : sel;
        sel = (hi16 == 2) ? rmax[2] : sel;
        sel = (hi16 == 3) ? rmax[3] : sel;
        out[OUT_OFF + i * 64 + lane] = fmaxf(sel + b2me, 0.f);
    }
}

// ---------------------------------------------------------------------------
extern "C" void kernel_launch(void* const* d_in, const int* in_sizes, int n_in,
                              void* d_out, int out_size, void* d_ws, size_t ws_size,
                              hipStream_t stream) {
    const float* x     = (const float*)d_in[0];
    const float* pos   = (const float*)d_in[1];
    const float* W1    = (const float*)d_in[3];
    const float* b1    = (const float*)d_in[4];
    const float* W2    = (const float*)d_in[5];
    const float* b2    = (const float*)d_in[6];
    float* out = (float*)d_out;
    (void)d_ws; (void)ws_size; (void)in_sizes; (void)n_in; (void)out_size;

    fused_kernel<<<dim3(NN / 8), dim3(256), 0, stream>>>(x, pos, W1, b1, W2, b2, out);
}